// Round 7
// baseline (20564.462 us; speedup 1.0000x reference)
//
#include <hip/hip_runtime.h>
#include <math.h>

#define N_ITERS 200
#define B_DIM 128
#define K_DIM 10000
#define KP2 10240           /* Z cols / Dth cols (k-dim padded) */
#define KB  10112           /* Dh rows / R stride: 79*128 */
#define D_DIM 1024
#define ALPHA_F 4.8828125e-6f   /* 0.01 / 2048 */

typedef unsigned short u16;
typedef __attribute__((ext_vector_type(8))) short bf16x8;
typedef __attribute__((ext_vector_type(4))) float f32x4;
#define MFMA __builtin_amdgcn_mfma_f32_16x16x32_bf16

__device__ __forceinline__ u16 f2bf(float x) {
    unsigned u = __float_as_uint(x);
    u += 0x7fff + ((u >> 16) & 1);
    return (u16)(u >> 16);
}
__device__ __forceinline__ float bf2f(u16 h) {
    return __uint_as_float(((unsigned)h) << 16);
}
__device__ __forceinline__ void split2(float x, u16& h, u16& l) {
    u16 hh = f2bf(x);
    h = hh;
    l = f2bf(x - bf2f(hh));
}
__device__ __forceinline__ int swz(int r) { return (r & 3) ^ ((r >> 2) & 1); }

__device__ __forceinline__ void gl2lds16(const u16* g, u16* l) {
    __builtin_amdgcn_global_load_lds(
        (const __attribute__((address_space(1))) unsigned int*)g,
        (__attribute__((address_space(3))) unsigned int*)l,
        16, 0, 0);
}

// ---------------------------------------------------------------------------
// init: out=0 (W + score), Zh/Zl=0, U0/U1=0, G=0, u0=0, scal=0
// ---------------------------------------------------------------------------
__global__ __launch_bounds__(256) void k_init(float* __restrict__ out,
                                              u16* __restrict__ Zh, u16* __restrict__ Zl,
                                              float* __restrict__ U0, float* __restrict__ U1,
                                              float* __restrict__ G,
                                              float* __restrict__ u0,
                                              float* __restrict__ scal) {
    int idx = blockIdx.x * 256 + threadIdx.x;
    int stride = gridDim.x * 256;
    for (int i = idx; i <= B_DIM * K_DIM; i += stride) out[i] = 0.0f;
    unsigned* zh = (unsigned*)Zh;
    unsigned* zl = (unsigned*)Zl;
    for (int i = idx; i < B_DIM * KP2 / 2; i += stride) { zh[i] = 0u; zl[i] = 0u; }
    for (int i = idx; i < B_DIM * D_DIM; i += stride) { U0[i] = 0.0f; U1[i] = 0.0f; }
    for (int i = idx; i < D_DIM * D_DIM; i += stride) G[i] = 0.0f;
    for (int i = idx; i < D_DIM; i += stride) u0[i] = 0.0f;
    for (int i = idx; i < 64; i += stride) scal[i] = 0.0f;
}

// ---------------------------------------------------------------------------
// D fp32 [10000,1024] -> Dh/Dl [KB,1024] and Dth/Dtl [1024,KP2] (pads zero)
// ---------------------------------------------------------------------------
__global__ __launch_bounds__(256) void k_convertD(const float* __restrict__ D,
                                                  u16* __restrict__ Dh,
                                                  u16* __restrict__ Dl,
                                                  u16* __restrict__ Dth,
                                                  u16* __restrict__ Dtl) {
    __shared__ u16 Th[32][33], Tl[32][33];
    int tx = threadIdx.x & 31, ty = threadIdx.x >> 5;
    int k0 = blockIdx.x * 32, d0 = blockIdx.y * 32;
    #pragma unroll
    for (int r = 0; r < 4; ++r) {
        int krow = k0 + ty + r * 8;
        float val = (krow < K_DIM) ? D[(size_t)krow * D_DIM + d0 + tx] : 0.0f;
        u16 h, l; split2(val, h, l);
        if (krow < KB) {
            Dh[(size_t)krow * D_DIM + d0 + tx] = h;
            Dl[(size_t)krow * D_DIM + d0 + tx] = l;
        }
        Th[ty + r * 8][tx] = h;
        Tl[ty + r * 8][tx] = l;
    }
    __syncthreads();
    #pragma unroll
    for (int r = 0; r < 4; ++r) {
        int d = d0 + ty + r * 8;
        int k = k0 + tx;
        Dth[(size_t)d * KP2 + k] = Th[tx][ty + r * 8];
        Dtl[(size_t)d * KP2 + k] = Tl[tx][ty + r * 8];
    }
}

// ---------------------------------------------------------------------------
// u0 = ones(10000) @ D  (column sums, fp32)
// ---------------------------------------------------------------------------
__global__ __launch_bounds__(256) void k_colsum(const float* __restrict__ D,
                                                float* __restrict__ u0) {
    int t = threadIdx.x;
    int kbase = blockIdx.x * 40;
    float a0 = 0.f, a1 = 0.f, a2 = 0.f, a3 = 0.f;
    for (int k = kbase; k < kbase + 40; ++k) {
        const float* row = D + (size_t)k * D_DIM;
        a0 += row[t];
        a1 += row[t + 256];
        a2 += row[t + 512];
        a3 += row[t + 768];
    }
    atomicAdd(&u0[t], a0);
    atomicAdd(&u0[t + 256], a1);
    atomicAdd(&u0[t + 512], a2);
    atomicAdd(&u0[t + 768], a3);
}

// ---------------------------------------------------------------------------
// k_mm: out[arow0+0:128][brow0+0:128] += A[128,K-chunk] @ B[128,K-chunk]^T
// Both operands K-major split-bf16. 256 thr / 4 waves, each wave 64x64.
// Stage (32 KB): Ah@0 Al@4096 Bh@8192 Bl@12288 (u16 units); dbuf stride 16384.
// grid: (.x = B row tile, .y = A row tile, .z = K split of ksteps*32)
// Used for: G1 (A=Z, B=Dth, out=U[128,1024])  and Gram (A=B=Dth, out=G).
// ---------------------------------------------------------------------------
__global__ __launch_bounds__(256, 2) void k_mm(const u16* Ah_g, const u16* Al_g, long sA,
                                               const u16* Bh_g, const u16* Bl_g, long sB,
                                               int ksteps, float* __restrict__ out,
                                               int outStride) {
    __shared__ __align__(16) u16 lds[32768];
    int t = threadIdx.x;
    int arow0 = blockIdx.y * 128;
    int brow0 = blockIdx.x * 128;
    size_t k0 = (size_t)blockIdx.z * ksteps * 32;

    int w4 = t >> 6, lane = t & 63, quad = lane >> 4, lr = lane & 15;
    int wm = (w4 >> 1) * 64, wn = (w4 & 1) * 64;

    // staging: wave w4 stages rows [w4*32, w4*32+32) of each array
    int rlo = w4 * 32 + (lane >> 2);
    int rhi = rlo + 16;
    int qs = lane & 3;
    const u16* sAh0 = Ah_g + (size_t)(arow0 + rlo) * sA + k0 + (qs ^ swz(rlo)) * 8;
    const u16* sAh1 = Ah_g + (size_t)(arow0 + rhi) * sA + k0 + (qs ^ swz(rhi)) * 8;
    const u16* sAl0 = Al_g + (size_t)(arow0 + rlo) * sA + k0 + (qs ^ swz(rlo)) * 8;
    const u16* sAl1 = Al_g + (size_t)(arow0 + rhi) * sA + k0 + (qs ^ swz(rhi)) * 8;
    const u16* sBh0 = Bh_g + (size_t)(brow0 + rlo) * sB + k0 + (qs ^ swz(rlo)) * 8;
    const u16* sBh1 = Bh_g + (size_t)(brow0 + rhi) * sB + k0 + (qs ^ swz(rhi)) * 8;
    const u16* sBl0 = Bl_g + (size_t)(brow0 + rlo) * sB + k0 + (qs ^ swz(rlo)) * 8;
    const u16* sBl1 = Bl_g + (size_t)(brow0 + rhi) * sB + k0 + (qs ^ swz(rhi)) * 8;
    int dbase = w4 * 1024 + lane * 8;   // u16 units; + li*512 per 16-row group

    int offAH[4], offAL[4], offBH[4], offBL[4];
    #pragma unroll
    for (int mi = 0; mi < 4; ++mi) {
        int rr = wm + mi * 16 + lr;
        int o = rr * 32 + ((quad ^ swz(rr)) * 8);
        offAH[mi] = o; offAL[mi] = 4096 + o;
    }
    #pragma unroll
    for (int ni = 0; ni < 4; ++ni) {
        int rr = wn + ni * 16 + lr;
        int o = rr * 32 + ((quad ^ swz(rr)) * 8);
        offBH[ni] = 8192 + o; offBL[ni] = 12288 + o;
    }

    f32x4 acc[4][4];
    #pragma unroll
    for (int mi = 0; mi < 4; ++mi)
        #pragma unroll
        for (int ni = 0; ni < 4; ++ni) acc[mi][ni] = (f32x4){0.f, 0.f, 0.f, 0.f};

    auto stage = [&](int s, int buf) {
        u16* b = lds + buf * 16384;
        size_t c = (size_t)s * 32;
        gl2lds16(sAh0 + c, b + dbase);
        gl2lds16(sAh1 + c, b + 512 + dbase);
        gl2lds16(sAl0 + c, b + 4096 + dbase);
        gl2lds16(sAl1 + c, b + 4608 + dbase);
        gl2lds16(sBh0 + c, b + 8192 + dbase);
        gl2lds16(sBh1 + c, b + 8704 + dbase);
        gl2lds16(sBl0 + c, b + 12288 + dbase);
        gl2lds16(sBl1 + c, b + 12800 + dbase);
    };

    stage(0, 0);
    for (int s = 0; s < ksteps; ++s) {
        __syncthreads();
        if (s + 1 < ksteps) stage(s + 1, (s + 1) & 1);
        u16* b = lds + (s & 1) * 16384;
        bf16x8 aH[4], aL[4], bH[4], bL[4];
        #pragma unroll
        for (int i = 0; i < 4; ++i) {
            aH[i] = *(const bf16x8*)&b[offAH[i]];
            aL[i] = *(const bf16x8*)&b[offAL[i]];
            bH[i] = *(const bf16x8*)&b[offBH[i]];
            bL[i] = *(const bf16x8*)&b[offBL[i]];
        }
        #pragma unroll
        for (int mi = 0; mi < 4; ++mi)
            #pragma unroll
            for (int ni = 0; ni < 4; ++ni) {
                acc[mi][ni] = MFMA(aL[mi], bH[ni], acc[mi][ni], 0, 0, 0);
                acc[mi][ni] = MFMA(aH[mi], bL[ni], acc[mi][ni], 0, 0, 0);
                acc[mi][ni] = MFMA(aH[mi], bH[ni], acc[mi][ni], 0, 0, 0);
            }
    }
    #pragma unroll
    for (int mi = 0; mi < 4; ++mi)
        #pragma unroll
        for (int ni = 0; ni < 4; ++ni) {
            int col = brow0 + wn + ni * 16 + lr;
            #pragma unroll
            for (int r = 0; r < 4; ++r) {
                int row = arow0 + wm + mi * 16 + quad * 4 + r;
                atomicAdd(&out[(size_t)row * outStride + col], acc[mi][ni][r]);
            }
        }
}

// ---------------------------------------------------------------------------
// One power step in u-space on Gram G: u = (pw==0)?u0 : wvin*rsqrt(Xprev);
// wvout[c] = sum_r u[r]*G[c][r]; X(pw) += wvout[c]*u[c].  grid 256 x 256.
// ---------------------------------------------------------------------------
__global__ __launch_bounds__(256) void k_pstep(const float* __restrict__ G,
                                               const float* __restrict__ u0,
                                               const float* __restrict__ wvin,
                                               float* __restrict__ wvout,
                                               float* __restrict__ scal, int pw) {
    int t = threadIdx.x;
    int c = blockIdx.x * 4 + (t >> 6);
    int lane = t & 63;
    float rsX = (pw > 0) ? rsqrtf(scal[1 + pw]) : 1.0f;
    float a = 0.f;
    const float* Gr = G + (size_t)c * D_DIM;
    #pragma unroll
    for (int j = 0; j < 16; ++j) {
        int r = lane + j * 64;
        float ur = (pw == 0) ? u0[r] : wvin[r] * rsX;
        a = fmaf(ur, Gr[r], a);
    }
    #pragma unroll
    for (int o = 32; o > 0; o >>= 1) a += __shfl_down(a, o, 64);
    if (lane == 0) {
        float uc = (pw == 0) ? u0[c] : wvin[c] * rsX;
        wvout[c] = a;
        atomicAdd(&scal[2 + pw], a * uc);
    }
}

__global__ void k_Lfin(float* __restrict__ scal) {
    float stepv = 1024.0f / sqrtf(scal[2 + 30]);
    scal[0] = stepv;
    scal[1] = stepv * ALPHA_F;
}

// ---------------------------------------------------------------------------
// k_g2: acc[128, n0:+128] = A_fp32[128,1024] @ Dh^T (split-bf16 compensated;
// A split on-the-fly during staging). grid 79 blocks, 256 thr, 4 waves 64x64.
// mode 0: R = acc/n.   mode 1: fused FISTA prox (W, Zh/Zl).  Zeroes Uz.
// ---------------------------------------------------------------------------
__global__ __launch_bounds__(256, 2) void k_g2(const float* __restrict__ Afp,
                                               const u16* __restrict__ Bh_g,
                                               const u16* __restrict__ Bl_g,
                                               float* __restrict__ R,
                                               float* __restrict__ W,
                                               u16* __restrict__ Zh, u16* __restrict__ Zl,
                                               const float* __restrict__ scal,
                                               float mom, int mode, int writeW,
                                               float* __restrict__ Uz) {
    __shared__ __align__(16) u16 lds[32768];
    int t = threadIdx.x;
    int n0 = blockIdx.x * 128;
    int w4 = t >> 6, lane = t & 63, quad = lane >> 4, lr = lane & 15;
    int wm = (w4 >> 1) * 64, wn = (w4 & 1) * 64;

    // B staging (async, bf16 pairs)
    int rlo = w4 * 32 + (lane >> 2);
    int rhi = rlo + 16;
    int qs = lane & 3;
    const u16* sBh0 = Bh_g + (size_t)(n0 + rlo) * D_DIM + (qs ^ swz(rlo)) * 8;
    const u16* sBh1 = Bh_g + (size_t)(n0 + rhi) * D_DIM + (qs ^ swz(rhi)) * 8;
    const u16* sBl0 = Bl_g + (size_t)(n0 + rlo) * D_DIM + (qs ^ swz(rlo)) * 8;
    const u16* sBl1 = Bl_g + (size_t)(n0 + rhi) * D_DIM + (qs ^ swz(rhi)) * 8;
    int dbase = w4 * 1024 + lane * 8;

    // A staging (fp32 -> split pair, manual ds_write)
    int ar = t >> 1, ah = t & 1;
    const float* sA = Afp + (size_t)ar * D_DIM + ah * 16;
    int adst0 = ar * 32 + (((ah * 2) ^ swz(ar)) * 8);
    int adst1 = ar * 32 + (((ah * 2 + 1) ^ swz(ar)) * 8);

    int offAH[4], offAL[4], offBH[4], offBL[4];
    #pragma unroll
    for (int mi = 0; mi < 4; ++mi) {
        int rr = wm + mi * 16 + lr;
        int o = rr * 32 + ((quad ^ swz(rr)) * 8);
        offAH[mi] = o; offAL[mi] = 4096 + o;
    }
    #pragma unroll
    for (int ni = 0; ni < 4; ++ni) {
        int rr = wn + ni * 16 + lr;
        int o = rr * 32 + ((quad ^ swz(rr)) * 8);
        offBH[ni] = 8192 + o; offBL[ni] = 12288 + o;
    }

    f32x4 acc[4][4];
    #pragma unroll
    for (int mi = 0; mi < 4; ++mi)
        #pragma unroll
        for (int ni = 0; ni < 4; ++ni) acc[mi][ni] = (f32x4){0.f, 0.f, 0.f, 0.f};

    auto stage = [&](int s, int buf) {
        u16* b = lds + buf * 16384;
        // B: async bf16 copy
        size_t c = (size_t)s * 32;
        gl2lds16(sBh0 + c, b + 8192 + dbase);
        gl2lds16(sBh1 + c, b + 8704 + dbase);
        gl2lds16(sBl0 + c, b + 12288 + dbase);
        gl2lds16(sBl1 + c, b + 12800 + dbase);
        // A: fp32 load + split + ds_write
        const float* p = sA + s * 32;
        float v[16];
        *(float4*)&v[0]  = *(const float4*)(p);
        *(float4*)&v[4]  = *(const float4*)(p + 4);
        *(float4*)&v[8]  = *(const float4*)(p + 8);
        *(float4*)&v[12] = *(const float4*)(p + 12);
        union { u16 us[16]; int4 q[2]; } hu, lu;
        #pragma unroll
        for (int j = 0; j < 16; ++j) split2(v[j], hu.us[j], lu.us[j]);
        *(int4*)&b[adst0] = hu.q[0];
        *(int4*)&b[adst1] = hu.q[1];
        *(int4*)&b[4096 + adst0] = lu.q[0];
        *(int4*)&b[4096 + adst1] = lu.q[1];
    };

    stage(0, 0);
    for (int s = 0; s < 32; ++s) {
        __syncthreads();
        if (s + 1 < 32) stage(s + 1, (s + 1) & 1);
        u16* b = lds + (s & 1) * 16384;
        bf16x8 aH[4], aL[4], bH[4], bL[4];
        #pragma unroll
        for (int i = 0; i < 4; ++i) {
            aH[i] = *(const bf16x8*)&b[offAH[i]];
            aL[i] = *(const bf16x8*)&b[offAL[i]];
            bH[i] = *(const bf16x8*)&b[offBH[i]];
            bL[i] = *(const bf16x8*)&b[offBL[i]];
        }
        #pragma unroll
        for (int mi = 0; mi < 4; ++mi)
            #pragma unroll
            for (int ni = 0; ni < 4; ++ni) {
                acc[mi][ni] = MFMA(aL[mi], bH[ni], acc[mi][ni], 0, 0, 0);
                acc[mi][ni] = MFMA(aH[mi], bL[ni], acc[mi][ni], 0, 0, 0);
                acc[mi][ni] = MFMA(aH[mi], bH[ni], acc[mi][ni], 0, 0, 0);
            }
    }

    const float invN = 1.0f / 1024.0f;
    if (mode == 0) {
        #pragma unroll
        for (int mi = 0; mi < 4; ++mi)
            #pragma unroll
            for (int ni = 0; ni < 4; ++ni) {
                int k = n0 + wn + ni * 16 + lr;
                #pragma unroll
                for (int r = 0; r < 4; ++r) {
                    int i = wm + mi * 16 + quad * 4 + r;
                    R[(size_t)i * KB + k] = acc[mi][ni][r] * invN;
                }
            }
    } else {
        float stepv = scal[0], th = scal[1];
        #pragma unroll
        for (int mi = 0; mi < 4; ++mi)
            #pragma unroll
            for (int ni = 0; ni < 4; ++ni) {
                int k = n0 + wn + ni * 16 + lr;
                #pragma unroll
                for (int r = 0; r < 4; ++r) {
                    int i = wm + mi * 16 + quad * 4 + r;
                    size_t iz = (size_t)i * KP2 + k;
                    float g = acc[mi][ni][r] * invN - R[(size_t)i * KB + k];
                    float z = bf2f(Zh[iz]) + bf2f(Zl[iz]);
                    float wold = (k < K_DIM) ? W[(size_t)i * K_DIM + k] : 0.0f;
                    float wnew = fmaxf(z - stepv * g - th, 0.0f);
                    float zn = wnew + mom * (wnew - wold);
                    if (k < K_DIM) W[(size_t)i * K_DIM + k] = wnew;
                    u16 h, l;
                    split2(writeW ? wnew : zn, h, l);
                    Zh[iz] = h; Zl[iz] = l;
                }
            }
    }
    // zero the U buffer for the NEXT iteration's k_mm accumulate
    for (int i = blockIdx.x * 256 + t; i < B_DIM * D_DIM; i += gridDim.x * 256)
        Uz[i] = 0.0f;
}

// ---------------------------------------------------------------------------
// score = sum_i <recon_i, emb_i> / (||recon_i|| + 1e-12); recon fp32 in U
// ---------------------------------------------------------------------------
__global__ __launch_bounds__(256) void k_score(const float* __restrict__ U,
                                               const float* __restrict__ emb,
                                               float* __restrict__ score) {
    int wid = blockIdx.x * 4 + (threadIdx.x >> 6);
    int lane = threadIdx.x & 63;
    if (wid >= B_DIM) return;
    float rr = 0.f, re = 0.f;
    #pragma unroll
    for (int j = 0; j < D_DIM; j += 64) {
        int idx = wid * D_DIM + j + lane;
        float x = U[idx];
        rr = fmaf(x, x, rr);
        re = fmaf(x, emb[idx], re);
    }
    #pragma unroll
    for (int off = 32; off > 0; off >>= 1) {
        rr += __shfl_down(rr, off, 64);
        re += __shfl_down(re, off, 64);
    }
    if (lane == 0) atomicAdd(score, re / (sqrtf(rr) + 1e-12f));
}

// ---------------------------------------------------------------------------
extern "C" void kernel_launch(void* const* d_in, const int* in_sizes, int n_in,
                              void* d_out, int out_size, void* d_ws, size_t ws_size,
                              hipStream_t stream) {
    const float* emb = (const float*)d_in[0];   // [128,1024]
    const float* Dm  = (const float*)d_in[1];   // [10000,1024]
    float* out = (float*)d_out;
    float* W = out;                             // [128][10000] in d_out

    size_t off = 0;
    auto carve = [&](size_t bytes) -> void* {
        void* r = (char*)d_ws + off;
        off += (bytes + 255) & ~(size_t)255;
        return r;
    };
    float* R    = (float*)carve((size_t)B_DIM * KB * 4);     // 5.18 MB (G aliases first 4 MB)
    float* U0   = (float*)carve((size_t)B_DIM * D_DIM * 4);  // 0.52 MB
    float* U1   = (float*)carve((size_t)B_DIM * D_DIM * 4);
    u16*   Zh   = (u16*)carve((size_t)B_DIM * KP2 * 2);      // 2.62 MB
    u16*   Zl   = (u16*)carve((size_t)B_DIM * KP2 * 2);
    float* u0   = (float*)carve(D_DIM * 4);
    float* wva  = (float*)carve(D_DIM * 4);
    float* wvb  = (float*)carve(D_DIM * 4);
    float* scal = (float*)carve(64 * 4);
    u16*   Dh   = (u16*)carve((size_t)KB * D_DIM * 2);       // 20.7 MB
    u16*   Dl   = (u16*)carve((size_t)KB * D_DIM * 2);
    u16*   Dth  = (u16*)carve((size_t)D_DIM * KP2 * 2);      // 21.0 MB
    u16*   Dtl  = (u16*)carve((size_t)D_DIM * KP2 * 2);
    float* G    = R;    // alias: Gram lives in R's space until R is written

    k_init<<<512, 256, 0, stream>>>(out, Zh, Zl, U0, U1, G, u0, scal);
    k_convertD<<<dim3(320, 32), 256, 0, stream>>>(Dm, Dh, Dl, Dth, Dtl);
    k_colsum<<<250, 256, 0, stream>>>(Dm, u0);

    // Gram G = Dth @ Dth^T (1024x1024 over K=10240), split-K=4, atomic accum
    k_mm<<<dim3(8, 8, 4), 256, 0, stream>>>(Dth, Dtl, (long)KP2,
                                            Dth, Dtl, (long)KP2,
                                            80, G, D_DIM);

    // power iteration in u-space
    for (int pw = 0; pw <= 30; ++pw) {
        float* win  = (pw & 1) ? wva : wvb;
        float* wout = (pw & 1) ? wvb : wva;
        k_pstep<<<256, 256, 0, stream>>>(G, u0, win, wout, scal, pw);
    }
    k_Lfin<<<1, 1, 0, stream>>>(scal);

    // R = emb @ D^T / n  (overwrites G region; also zeroes U0 for iter 0)
    k_g2<<<79, 256, 0, stream>>>(emb, Dh, Dl, R, W, Zh, Zl, scal, 0.0f, 0, 0, U0);

    // ---- FISTA ----
    double t = 1.0;
    for (int it = 0; it < N_ITERS; ++it) {
        double tn = 0.5 * (1.0 + sqrt(1.0 + 4.0 * t * t));
        float mom = (float)((t - 1.0) / tn);
        t = tn;
        float* Ucur  = (it & 1) ? U1 : U0;
        float* Unext = (it & 1) ? U0 : U1;
        k_mm<<<dim3(8, 1, 32), 256, 0, stream>>>(Zh, Zl, (long)KP2,
                                                 Dth, Dtl, (long)KP2,
                                                 10, Ucur, D_DIM);
        k_g2<<<79, 256, 0, stream>>>(Ucur, Dh, Dl, R, W, Zh, Zl, scal, mom, 1,
                                     (it == N_ITERS - 1) ? 1 : 0, Unext);
    }

    // recon = W@D (Zh/Zl hold split W; U0 zeroed by last k_g2), then score
    k_mm<<<dim3(8, 1, 32), 256, 0, stream>>>(Zh, Zl, (long)KP2,
                                             Dth, Dtl, (long)KP2,
                                             10, U0, D_DIM);
    k_score<<<32, 256, 0, stream>>>(U0, emb, out + (size_t)B_DIM * K_DIM);
}

// Round 8
// 12232.654 us; speedup vs baseline: 1.6811x; 1.6811x over previous
//
#include <hip/hip_runtime.h>
#include <math.h>

#define N_ITERS 200
#define B_DIM 128
#define K_DIM 10000
#define KP2 10240           /* Z cols / Dth cols (contraction dim, 16x640) */
#define KB  10112           /* Dh rows / G2 col range: 316 x 32 */
#define D_DIM 1024
#define ALPHA_F 4.8828125e-6f   /* 0.01 / 2048 */
#define NPART 16            /* G1 k-split partials */

typedef unsigned short u16;
typedef __attribute__((ext_vector_type(8))) short bf16x8;
typedef __attribute__((ext_vector_type(4))) float f32x4;
#define MFMA __builtin_amdgcn_mfma_f32_16x16x32_bf16

__device__ __forceinline__ u16 f2bf(float x) {
    unsigned u = __float_as_uint(x);
    u += 0x7fff + ((u >> 16) & 1);
    return (u16)(u >> 16);
}
__device__ __forceinline__ float bf2f(u16 h) {
    return __uint_as_float(((unsigned)h) << 16);
}
__device__ __forceinline__ void split2(float x, u16& h, u16& l) {
    u16 hh = f2bf(x);
    h = hh;
    l = f2bf(x - bf2f(hh));
}
__device__ __forceinline__ int swz(int r) { return (r & 3) ^ ((r >> 2) & 1); }

__device__ __forceinline__ void gl2lds16(const u16* g, u16* l) {
    __builtin_amdgcn_global_load_lds(
        (const __attribute__((address_space(1))) unsigned int*)g,
        (__attribute__((address_space(3))) unsigned int*)l,
        16, 0, 0);
}

// ---------------------------------------------------------------------------
// init: out (W+score)=0, Zh/Zl=0, Up (Gram region)=0, u0=0, scal=0
// ---------------------------------------------------------------------------
__global__ __launch_bounds__(256) void k_init(float* __restrict__ out,
                                              u16* __restrict__ Zh, u16* __restrict__ Zl,
                                              float* __restrict__ Up,
                                              float* __restrict__ u0,
                                              float* __restrict__ scal) {
    int idx = blockIdx.x * 256 + threadIdx.x;
    int stride = gridDim.x * 256;
    for (int i = idx; i <= B_DIM * K_DIM; i += stride) out[i] = 0.0f;
    unsigned* zh = (unsigned*)Zh;
    unsigned* zl = (unsigned*)Zl;
    for (int i = idx; i < B_DIM * KP2 / 2; i += stride) { zh[i] = 0u; zl[i] = 0u; }
    for (int i = idx; i < NPART * B_DIM * D_DIM; i += stride) Up[i] = 0.0f;
    for (int i = idx; i < D_DIM; i += stride) u0[i] = 0.0f;
    for (int i = idx; i < 64; i += stride) scal[i] = 0.0f;
}

// ---------------------------------------------------------------------------
// D fp32 [10000,1024] -> Dh/Dl [KB,1024] and Dth/Dtl [1024,KP2] (pads zero)
// ---------------------------------------------------------------------------
__global__ __launch_bounds__(256) void k_convertD(const float* __restrict__ D,
                                                  u16* __restrict__ Dh,
                                                  u16* __restrict__ Dl,
                                                  u16* __restrict__ Dth,
                                                  u16* __restrict__ Dtl) {
    __shared__ u16 Th[32][33], Tl[32][33];
    int tx = threadIdx.x & 31, ty = threadIdx.x >> 5;
    int k0 = blockIdx.x * 32, d0 = blockIdx.y * 32;
    #pragma unroll
    for (int r = 0; r < 4; ++r) {
        int krow = k0 + ty + r * 8;
        float val = (krow < K_DIM) ? D[(size_t)krow * D_DIM + d0 + tx] : 0.0f;
        u16 h, l; split2(val, h, l);
        if (krow < KB) {
            Dh[(size_t)krow * D_DIM + d0 + tx] = h;
            Dl[(size_t)krow * D_DIM + d0 + tx] = l;
        }
        Th[ty + r * 8][tx] = h;
        Tl[ty + r * 8][tx] = l;
    }
    __syncthreads();
    #pragma unroll
    for (int r = 0; r < 4; ++r) {
        int d = d0 + ty + r * 8;
        int k = k0 + tx;
        Dth[(size_t)d * KP2 + k] = Th[tx][ty + r * 8];
        Dtl[(size_t)d * KP2 + k] = Tl[tx][ty + r * 8];
    }
}

// ---------------------------------------------------------------------------
// u0 = ones(10000) @ D  (column sums, fp32)
// ---------------------------------------------------------------------------
__global__ __launch_bounds__(256) void k_colsum(const float* __restrict__ D,
                                                float* __restrict__ u0) {
    int t = threadIdx.x;
    int kbase = blockIdx.x * 40;
    float a0 = 0.f, a1 = 0.f, a2 = 0.f, a3 = 0.f;
    for (int k = kbase; k < kbase + 40; ++k) {
        const float* row = D + (size_t)k * D_DIM;
        a0 += row[t];
        a1 += row[t + 256];
        a2 += row[t + 512];
        a3 += row[t + 768];
    }
    atomicAdd(&u0[t], a0);
    atomicAdd(&u0[t + 256], a1);
    atomicAdd(&u0[t + 512], a2);
    atomicAdd(&u0[t + 768], a3);
}

// ---------------------------------------------------------------------------
// k_mm (Gram only): G[128-tile][128-tile] += Dth-rows @ Dth-rows^T
// 256 thr / 4 waves of 64x64; atomic accumulate (4-way, one-time cost).
// grid (.x = B row tile, .y = A row tile, .z = K split)
// ---------------------------------------------------------------------------
__global__ __launch_bounds__(256, 2) void k_mm(const u16* Ah_g, const u16* Al_g, long sA,
                                               const u16* Bh_g, const u16* Bl_g, long sB,
                                               int ksteps, float* __restrict__ out,
                                               int outStride) {
    __shared__ __align__(16) u16 lds[32768];
    int t = threadIdx.x;
    int arow0 = blockIdx.y * 128;
    int brow0 = blockIdx.x * 128;
    size_t k0 = (size_t)blockIdx.z * ksteps * 32;

    int w4 = t >> 6, lane = t & 63, quad = lane >> 4, lr = lane & 15;
    int wm = (w4 >> 1) * 64, wn = (w4 & 1) * 64;

    int rlo = w4 * 32 + (lane >> 2);
    int rhi = rlo + 16;
    int qs = lane & 3;
    const u16* sAh0 = Ah_g + (size_t)(arow0 + rlo) * sA + k0 + (qs ^ swz(rlo)) * 8;
    const u16* sAh1 = Ah_g + (size_t)(arow0 + rhi) * sA + k0 + (qs ^ swz(rhi)) * 8;
    const u16* sAl0 = Al_g + (size_t)(arow0 + rlo) * sA + k0 + (qs ^ swz(rlo)) * 8;
    const u16* sAl1 = Al_g + (size_t)(arow0 + rhi) * sA + k0 + (qs ^ swz(rhi)) * 8;
    const u16* sBh0 = Bh_g + (size_t)(brow0 + rlo) * sB + k0 + (qs ^ swz(rlo)) * 8;
    const u16* sBh1 = Bh_g + (size_t)(brow0 + rhi) * sB + k0 + (qs ^ swz(rhi)) * 8;
    const u16* sBl0 = Bl_g + (size_t)(brow0 + rlo) * sB + k0 + (qs ^ swz(rlo)) * 8;
    const u16* sBl1 = Bl_g + (size_t)(brow0 + rhi) * sB + k0 + (qs ^ swz(rhi)) * 8;
    int dbase = w4 * 1024 + lane * 8;

    int offAH[4], offAL[4], offBH[4], offBL[4];
    #pragma unroll
    for (int mi = 0; mi < 4; ++mi) {
        int rr = wm + mi * 16 + lr;
        int o = rr * 32 + ((quad ^ swz(rr)) * 8);
        offAH[mi] = o; offAL[mi] = 4096 + o;
    }
    #pragma unroll
    for (int ni = 0; ni < 4; ++ni) {
        int rr = wn + ni * 16 + lr;
        int o = rr * 32 + ((quad ^ swz(rr)) * 8);
        offBH[ni] = 8192 + o; offBL[ni] = 12288 + o;
    }

    f32x4 acc[4][4];
    #pragma unroll
    for (int mi = 0; mi < 4; ++mi)
        #pragma unroll
        for (int ni = 0; ni < 4; ++ni) acc[mi][ni] = (f32x4){0.f, 0.f, 0.f, 0.f};

    auto stage = [&](int s, int buf) {
        u16* b = lds + buf * 16384;
        size_t c = (size_t)s * 32;
        gl2lds16(sAh0 + c, b + dbase);
        gl2lds16(sAh1 + c, b + 512 + dbase);
        gl2lds16(sAl0 + c, b + 4096 + dbase);
        gl2lds16(sAl1 + c, b + 4608 + dbase);
        gl2lds16(sBh0 + c, b + 8192 + dbase);
        gl2lds16(sBh1 + c, b + 8704 + dbase);
        gl2lds16(sBl0 + c, b + 12288 + dbase);
        gl2lds16(sBl1 + c, b + 12800 + dbase);
    };

    stage(0, 0);
    for (int s = 0; s < ksteps; ++s) {
        __syncthreads();
        if (s + 1 < ksteps) stage(s + 1, (s + 1) & 1);
        u16* b = lds + (s & 1) * 16384;
        bf16x8 aH[4], aL[4], bH[4], bL[4];
        #pragma unroll
        for (int i = 0; i < 4; ++i) {
            aH[i] = *(const bf16x8*)&b[offAH[i]];
            aL[i] = *(const bf16x8*)&b[offAL[i]];
            bH[i] = *(const bf16x8*)&b[offBH[i]];
            bL[i] = *(const bf16x8*)&b[offBL[i]];
        }
        #pragma unroll
        for (int mi = 0; mi < 4; ++mi)
            #pragma unroll
            for (int ni = 0; ni < 4; ++ni) {
                acc[mi][ni] = MFMA(aL[mi], bH[ni], acc[mi][ni], 0, 0, 0);
                acc[mi][ni] = MFMA(aH[mi], bL[ni], acc[mi][ni], 0, 0, 0);
                acc[mi][ni] = MFMA(aH[mi], bH[ni], acc[mi][ni], 0, 0, 0);
            }
    }
    #pragma unroll
    for (int mi = 0; mi < 4; ++mi)
        #pragma unroll
        for (int ni = 0; ni < 4; ++ni) {
            int col = brow0 + wn + ni * 16 + lr;
            #pragma unroll
            for (int r = 0; r < 4; ++r) {
                int row = arow0 + wm + mi * 16 + quad * 4 + r;
                atomicAdd(&out[(size_t)row * outStride + col], acc[mi][ni][r]);
            }
        }
}

// ---------------------------------------------------------------------------
// power step in u-space on Gram G. grid 256 x 256.
// ---------------------------------------------------------------------------
__global__ __launch_bounds__(256) void k_pstep(const float* __restrict__ G,
                                               const float* __restrict__ u0,
                                               const float* __restrict__ wvin,
                                               float* __restrict__ wvout,
                                               float* __restrict__ scal, int pw) {
    int t = threadIdx.x;
    int c = blockIdx.x * 4 + (t >> 6);
    int lane = t & 63;
    float rsX = (pw > 0) ? rsqrtf(scal[1 + pw]) : 1.0f;
    float a = 0.f;
    const float* Gr = G + (size_t)c * D_DIM;
    #pragma unroll
    for (int j = 0; j < 16; ++j) {
        int r = lane + j * 64;
        float ur = (pw == 0) ? u0[r] : wvin[r] * rsX;
        a = fmaf(ur, Gr[r], a);
    }
    #pragma unroll
    for (int o = 32; o > 0; o >>= 1) a += __shfl_down(a, o, 64);
    if (lane == 0) {
        float uc = (pw == 0) ? u0[c] : wvin[c] * rsX;
        wvout[c] = a;
        atomicAdd(&scal[2 + pw], a * uc);
    }
}

__global__ void k_Lfin(float* __restrict__ scal) {
    float stepv = 1024.0f / sqrtf(scal[2 + 30]);
    scal[0] = stepv;
    scal[1] = stepv * ALPHA_F;
}

// ---------------------------------------------------------------------------
// k_g1: Up[ks][128][n0:n0+64] = Z[128, ks*640:+640] @ Dth-rows^T
// grid (16 n-tiles of 64, 16 ksplits), 256 thr / 4 waves of 64x32, 20 ksteps.
// LDS/stage (u16): Ah@0[128][32] Al@4096 Bh@8192[64][32] Bl@10240; x2 dbuf.
// ---------------------------------------------------------------------------
__global__ __launch_bounds__(256, 2) void k_g1(const u16* __restrict__ Zh,
                                               const u16* __restrict__ Zl,
                                               const u16* __restrict__ Dth,
                                               const u16* __restrict__ Dtl,
                                               float* __restrict__ Up) {
    __shared__ __align__(16) u16 lds[24576];
    int t = threadIdx.x;
    int n0 = blockIdx.x * 64;
    int ks = blockIdx.y;
    size_t kbase = (size_t)ks * 640;
    int w = t >> 6, lane = t & 63, quad = lane >> 4, lr = lane & 15;
    int wm = (w >> 1) * 64, wn = (w & 1) * 32;
    int rl = lane >> 2, qs = lane & 3;

    int rA0 = w * 32 + rl, rA1 = rA0 + 16;
    int rB  = w * 16 + rl;
    const u16* pAh0 = Zh + (size_t)rA0 * KP2 + kbase + (qs ^ swz(rA0)) * 8;
    const u16* pAh1 = Zh + (size_t)rA1 * KP2 + kbase + (qs ^ swz(rA1)) * 8;
    const u16* pAl0 = Zl + (size_t)rA0 * KP2 + kbase + (qs ^ swz(rA0)) * 8;
    const u16* pAl1 = Zl + (size_t)rA1 * KP2 + kbase + (qs ^ swz(rA1)) * 8;
    const u16* pBh  = Dth + (size_t)(n0 + rB) * KP2 + kbase + (qs ^ swz(rB)) * 8;
    const u16* pBl  = Dtl + (size_t)(n0 + rB) * KP2 + kbase + (qs ^ swz(rB)) * 8;
    int dA0 = w * 1024 + lane * 8;
    int dA1 = dA0 + 512;
    int dB  = w * 512 + lane * 8;

    int offAH[4], offAL[4], offBH[2], offBL[2];
    #pragma unroll
    for (int mi = 0; mi < 4; ++mi) {
        int rr = wm + mi * 16 + lr;
        int o = rr * 32 + ((quad ^ swz(rr)) * 8);
        offAH[mi] = o; offAL[mi] = 4096 + o;
    }
    #pragma unroll
    for (int ni = 0; ni < 2; ++ni) {
        int rr = wn + ni * 16 + lr;
        int o = rr * 32 + ((quad ^ swz(rr)) * 8);
        offBH[ni] = 8192 + o; offBL[ni] = 10240 + o;
    }

    f32x4 acc[4][2];
    #pragma unroll
    for (int mi = 0; mi < 4; ++mi)
        #pragma unroll
        for (int ni = 0; ni < 2; ++ni) acc[mi][ni] = (f32x4){0.f, 0.f, 0.f, 0.f};

    auto stage = [&](int s, int buf) {
        u16* b = lds + buf * 12288;
        size_t c = (size_t)s * 32;
        gl2lds16(pAh0 + c, b + dA0);
        gl2lds16(pAh1 + c, b + dA1);
        gl2lds16(pAl0 + c, b + 4096 + dA0);
        gl2lds16(pAl1 + c, b + 4096 + dA1);
        gl2lds16(pBh + c, b + 8192 + dB);
        gl2lds16(pBl + c, b + 10240 + dB);
    };

    stage(0, 0);
    for (int s = 0; s < 20; ++s) {
        __syncthreads();
        if (s + 1 < 20) stage(s + 1, (s + 1) & 1);
        u16* b = lds + (s & 1) * 12288;
        bf16x8 aH[4], aL[4], bH[2], bL[2];
        #pragma unroll
        for (int i = 0; i < 4; ++i) {
            aH[i] = *(const bf16x8*)&b[offAH[i]];
            aL[i] = *(const bf16x8*)&b[offAL[i]];
        }
        #pragma unroll
        for (int i = 0; i < 2; ++i) {
            bH[i] = *(const bf16x8*)&b[offBH[i]];
            bL[i] = *(const bf16x8*)&b[offBL[i]];
        }
        #pragma unroll
        for (int mi = 0; mi < 4; ++mi)
            #pragma unroll
            for (int ni = 0; ni < 2; ++ni) {
                acc[mi][ni] = MFMA(aL[mi], bH[ni], acc[mi][ni], 0, 0, 0);
                acc[mi][ni] = MFMA(aH[mi], bL[ni], acc[mi][ni], 0, 0, 0);
                acc[mi][ni] = MFMA(aH[mi], bH[ni], acc[mi][ni], 0, 0, 0);
            }
    }
    float* o = Up + (size_t)ks * (B_DIM * D_DIM);
    #pragma unroll
    for (int mi = 0; mi < 4; ++mi)
        #pragma unroll
        for (int ni = 0; ni < 2; ++ni) {
            int d = n0 + wn + ni * 16 + lr;
            #pragma unroll
            for (int r = 0; r < 4; ++r) {
                int row = wm + mi * 16 + quad * 4 + r;
                o[(size_t)row * D_DIM + d] = acc[mi][ni][r];
            }
        }
}

// ---------------------------------------------------------------------------
// reduce NPART partials, optionally subtract emb (residual), split -> Uh/Ul
// ---------------------------------------------------------------------------
__global__ __launch_bounds__(256) void k_reduceU(const float* __restrict__ Up,
                                                 const float* __restrict__ emb,
                                                 u16* __restrict__ Uh,
                                                 u16* __restrict__ Ul,
                                                 int subEmb) {
    int base = (blockIdx.x * 256 + threadIdx.x) * 8;
    float4 s0 = {0, 0, 0, 0}, s1 = {0, 0, 0, 0};
    #pragma unroll
    for (int s = 0; s < NPART; ++s) {
        const float* p = Up + (size_t)s * (B_DIM * D_DIM) + base;
        float4 a = *(const float4*)p;
        float4 b = *(const float4*)(p + 4);
        s0.x += a.x; s0.y += a.y; s0.z += a.z; s0.w += a.w;
        s1.x += b.x; s1.y += b.y; s1.z += b.z; s1.w += b.w;
    }
    if (subEmb) {
        float4 e0 = *(const float4*)(emb + base);
        float4 e1 = *(const float4*)(emb + base + 4);
        s0.x -= e0.x; s0.y -= e0.y; s0.z -= e0.z; s0.w -= e0.w;
        s1.x -= e1.x; s1.y -= e1.y; s1.z -= e1.z; s1.w -= e1.w;
    }
    float vbuf[8] = {s0.x, s0.y, s0.z, s0.w, s1.x, s1.y, s1.z, s1.w};
    union { u16 us[8]; int4 v; } h, l;
    #pragma unroll
    for (int q = 0; q < 8; ++q) split2(vbuf[q], h.us[q], l.us[q]);
    *(int4*)&Uh[base] = h.v;
    *(int4*)&Ul[base] = l.v;
}

// ---------------------------------------------------------------------------
// k_g2: acc[128, n0:+32] = Ures[128,1024] @ Dh-rows^T ; fused FISTA prox.
// grid 316 x 128 thr (2 waves, wave-tile 64m x 32n), 32 ksteps.
// LDS/stage (u16): Ah@0[128][32] Al@4096 Bh@8192[32][32] Bl@9216; x2 dbuf.
// ---------------------------------------------------------------------------
__global__ __launch_bounds__(128, 2) void k_g2(const u16* __restrict__ Uh,
                                               const u16* __restrict__ Ul,
                                               const u16* __restrict__ Dh,
                                               const u16* __restrict__ Dl,
                                               float* __restrict__ W,
                                               u16* __restrict__ Zh, u16* __restrict__ Zl,
                                               const float* __restrict__ scal,
                                               float mom, int writeW) {
    __shared__ __align__(16) u16 lds[20480];
    int t = threadIdx.x;
    int n0 = blockIdx.x * 32;
    int w = t >> 6, lane = t & 63, quad = lane >> 4, lr = lane & 15;
    int rl = lane >> 2, qs = lane & 3;

    // A staging: wave w stages rows w*64 .. w*64+64 (4 calls of 16 rows)
    int rA = w * 64 + rl;
    const u16* pAh[4];
    const u16* pAl[4];
    #pragma unroll
    for (int j = 0; j < 4; ++j) {
        int r = rA + j * 16;
        pAh[j] = Uh + (size_t)r * D_DIM + (qs ^ swz(r)) * 8;
        pAl[j] = Ul + (size_t)r * D_DIM + (qs ^ swz(r)) * 8;
    }
    // B staging: wave w stages rows w*16 .. w*16+16 (1 call)
    int rB = w * 16 + rl;
    const u16* pBh = Dh + (size_t)(n0 + rB) * D_DIM + (qs ^ swz(rB)) * 8;
    const u16* pBl = Dl + (size_t)(n0 + rB) * D_DIM + (qs ^ swz(rB)) * 8;
    int dA = w * 2048 + lane * 8;
    int dB = w * 512 + lane * 8;

    int offAH[4], offAL[4], offBH[2], offBL[2];
    #pragma unroll
    for (int mi = 0; mi < 4; ++mi) {
        int rr = w * 64 + mi * 16 + lr;
        int o = rr * 32 + ((quad ^ swz(rr)) * 8);
        offAH[mi] = o; offAL[mi] = 4096 + o;
    }
    #pragma unroll
    for (int ni = 0; ni < 2; ++ni) {
        int rr = ni * 16 + lr;
        int o = rr * 32 + ((quad ^ swz(rr)) * 8);
        offBH[ni] = 8192 + o; offBL[ni] = 9216 + o;
    }

    f32x4 acc[4][2];
    #pragma unroll
    for (int mi = 0; mi < 4; ++mi)
        #pragma unroll
        for (int ni = 0; ni < 2; ++ni) acc[mi][ni] = (f32x4){0.f, 0.f, 0.f, 0.f};

    auto stage = [&](int s, int buf) {
        u16* b = lds + buf * 10240;
        size_t c = (size_t)s * 32;
        #pragma unroll
        for (int j = 0; j < 4; ++j) {
            gl2lds16(pAh[j] + c, b + dA + j * 512);
            gl2lds16(pAl[j] + c, b + 4096 + dA + j * 512);
        }
        gl2lds16(pBh + c, b + 8192 + dB);
        gl2lds16(pBl + c, b + 9216 + dB);
    };

    stage(0, 0);
    for (int s = 0; s < 32; ++s) {
        __syncthreads();
        if (s + 1 < 32) stage(s + 1, (s + 1) & 1);
        u16* b = lds + (s & 1) * 10240;
        bf16x8 aH[4], aL[4], bH[2], bL[2];
        #pragma unroll
        for (int i = 0; i < 4; ++i) {
            aH[i] = *(const bf16x8*)&b[offAH[i]];
            aL[i] = *(const bf16x8*)&b[offAL[i]];
        }
        #pragma unroll
        for (int i = 0; i < 2; ++i) {
            bH[i] = *(const bf16x8*)&b[offBH[i]];
            bL[i] = *(const bf16x8*)&b[offBL[i]];
        }
        #pragma unroll
        for (int mi = 0; mi < 4; ++mi)
            #pragma unroll
            for (int ni = 0; ni < 2; ++ni) {
                acc[mi][ni] = MFMA(aL[mi], bH[ni], acc[mi][ni], 0, 0, 0);
                acc[mi][ni] = MFMA(aH[mi], bL[ni], acc[mi][ni], 0, 0, 0);
                acc[mi][ni] = MFMA(aH[mi], bH[ni], acc[mi][ni], 0, 0, 0);
            }
    }

    const float invN = 1.0f / 1024.0f;
    float stepv = scal[0], th = scal[1];
    #pragma unroll
    for (int mi = 0; mi < 4; ++mi)
        #pragma unroll
        for (int ni = 0; ni < 2; ++ni) {
            int k = n0 + ni * 16 + lr;
            #pragma unroll
            for (int r = 0; r < 4; ++r) {
                int i = w * 64 + mi * 16 + quad * 4 + r;
                size_t iz = (size_t)i * KP2 + k;
                float g = acc[mi][ni][r] * invN;
                float z = bf2f(Zh[iz]) + bf2f(Zl[iz]);
                float wold = (k < K_DIM) ? W[(size_t)i * K_DIM + k] : 0.0f;
                float wnew = fmaxf(z - stepv * g - th, 0.0f);
                float zn = wnew + mom * (wnew - wold);
                if (k < K_DIM) W[(size_t)i * K_DIM + k] = wnew;
                u16 h, l;
                split2(writeW ? wnew : zn, h, l);
                Zh[iz] = h; Zl[iz] = l;
            }
        }
}

// ---------------------------------------------------------------------------
// score = sum_i <recon_i, emb_i> / (||recon_i|| + 1e-12); recon from split U
// ---------------------------------------------------------------------------
__global__ __launch_bounds__(256) void k_score(const u16* __restrict__ Uh,
                                               const u16* __restrict__ Ul,
                                               const float* __restrict__ emb,
                                               float* __restrict__ score) {
    int wid = blockIdx.x * 4 + (threadIdx.x >> 6);
    int lane = threadIdx.x & 63;
    if (wid >= B_DIM) return;
    float rr = 0.f, re = 0.f;
    #pragma unroll
    for (int j = 0; j < D_DIM; j += 64) {
        int idx = wid * D_DIM + j + lane;
        float x = bf2f(Uh[idx]) + bf2f(Ul[idx]);
        rr = fmaf(x, x, rr);
        re = fmaf(x, emb[idx], re);
    }
    #pragma unroll
    for (int off = 32; off > 0; off >>= 1) {
        rr += __shfl_down(rr, off, 64);
        re += __shfl_down(re, off, 64);
    }
    if (lane == 0) atomicAdd(score, re / (sqrtf(rr) + 1e-12f));
}

// ---------------------------------------------------------------------------
extern "C" void kernel_launch(void* const* d_in, const int* in_sizes, int n_in,
                              void* d_out, int out_size, void* d_ws, size_t ws_size,
                              hipStream_t stream) {
    const float* emb = (const float*)d_in[0];   // [128,1024]
    const float* Dm  = (const float*)d_in[1];   // [10000,1024]
    float* out = (float*)d_out;
    float* W = out;                             // [128][10000] in d_out

    size_t off = 0;
    auto carve = [&](size_t bytes) -> void* {
        void* r = (char*)d_ws + off;
        off += (bytes + 255) & ~(size_t)255;
        return r;
    };
    float* Up   = (float*)carve((size_t)NPART * B_DIM * D_DIM * 4);  // 8.39 MB
    u16*   Zh   = (u16*)carve((size_t)B_DIM * KP2 * 2);              // 2.62 MB
    u16*   Zl   = (u16*)carve((size_t)B_DIM * KP2 * 2);
    u16*   Uh   = (u16*)carve((size_t)B_DIM * D_DIM * 2);            // 0.26 MB
    u16*   Ul   = (u16*)carve((size_t)B_DIM * D_DIM * 2);
    float* u0   = (float*)carve(D_DIM * 4);
    float* wva  = (float*)carve(D_DIM * 4);
    float* wvb  = (float*)carve(D_DIM * 4);
    float* scal = (float*)carve(64 * 4);
    u16*   Dh   = (u16*)carve((size_t)KB * D_DIM * 2);               // 20.7 MB
    u16*   Dl   = (u16*)carve((size_t)KB * D_DIM * 2);
    u16*   Dth  = (u16*)carve((size_t)D_DIM * KP2 * 2);              // 21.0 MB
    u16*   Dtl  = (u16*)carve((size_t)D_DIM * KP2 * 2);
    float* G    = Up;   // Gram aliases Up (4.19 MB <= 8.39 MB), used pre-FISTA

    k_init<<<512, 256, 0, stream>>>(out, Zh, Zl, Up, u0, scal);
    k_convertD<<<dim3(320, 32), 256, 0, stream>>>(Dm, Dh, Dl, Dth, Dtl);
    k_colsum<<<250, 256, 0, stream>>>(Dm, u0);

    // Gram G = Dth @ Dth^T (1024x1024 over K=10240), split-K=4, atomic accum
    k_mm<<<dim3(8, 8, 4), 256, 0, stream>>>(Dth, Dtl, (long)KP2,
                                            Dth, Dtl, (long)KP2,
                                            80, G, D_DIM);

    // power iteration in u-space
    for (int pw = 0; pw <= 30; ++pw) {
        float* win  = (pw & 1) ? wva : wvb;
        float* wout = (pw & 1) ? wvb : wva;
        k_pstep<<<256, 256, 0, stream>>>(G, u0, win, wout, scal, pw);
    }
    k_Lfin<<<1, 1, 0, stream>>>(scal);

    // ---- FISTA ----
    double t = 1.0;
    for (int it = 0; it < N_ITERS; ++it) {
        double tn = 0.5 * (1.0 + sqrt(1.0 + 4.0 * t * t));
        float mom = (float)((t - 1.0) / tn);
        t = tn;
        k_g1<<<dim3(16, 16), 256, 0, stream>>>(Zh, Zl, Dth, Dtl, Up);
        k_reduceU<<<64, 256, 0, stream>>>(Up, emb, Uh, Ul, 1);
        k_g2<<<316, 128, 0, stream>>>(Uh, Ul, Dh, Dl, W, Zh, Zl, scal, mom,
                                      (it == N_ITERS - 1) ? 1 : 0);
    }

    // recon = W@D (Zh/Zl hold split W), then score
    k_g1<<<dim3(16, 16), 256, 0, stream>>>(Zh, Zl, Dth, Dtl, Up);
    k_reduceU<<<64, 256, 0, stream>>>(Up, emb, Uh, Ul, 0);
    k_score<<<32, 256, 0, stream>>>(Uh, Ul, emb, out + (size_t)B_DIM * K_DIM);
}